// Round 8
// baseline (19.146 us; speedup 1.0000x reference)
//
#include <hip/hip_runtime.h>

// GraphAttentionLayer collapses algebraically:
//   a[i,j] = s[i] (constant over j) => softmax row = uniform 1/N
//   out[i] = mean_j h[j] = (mean_j x[j]) @ W.T + b   (identical for every row i)
//
// Shape: TWO plain kernel nodes (measured: 3 nodes=23.8, 2 nodes=20.35->16.62,
// all 1-node in-kernel-sync variants 54-70us -> kernel boundary is the cheapest
// global barrier; node count + kernel critical path are the only levers left).
// This round: K2 latency-chain shortening (full-ILP reduce, no LDS W staging,
// all-fp32) + 256-block grids so the 4MB broadcast write uses every CU.

#define N_ROWS 8192
#define F_IN   256
#define F_OUT  128
#define NBLK   256
#define RPB    (N_ROWS / NBLK)   // 32 rows per block

// K1: partial column sums. part[p][c] f32, p<256, c<256 (256 KB), coalesced.
__global__ void __launch_bounds__(256)
gat_colsum(const float* __restrict__ x, float* __restrict__ part) {
    const int t = threadIdx.x, blk = blockIdx.x;
    const float* xp = x + (size_t)blk * RPB * F_IN + t;
    float s = 0.f;
#pragma unroll
    for (int r = 0; r < RPB; ++r)
        s += xp[r * F_IN];               // coalesced, 1KB/row
    part[blk * F_IN + t] = s;
}

// K2: redundant deterministic reduce + matvec + broadcast. 256 blocks x 256 thr.
__global__ void __launch_bounds__(256)
gat_finish(const float* __restrict__ part, const float* __restrict__ W,
           const float* __restrict__ b, float* __restrict__ out) {
    __shared__ float xbar[F_IN];
    __shared__ float psum[256];
    __shared__ float mrow[F_OUT];
    const int t = threadIdx.x;

    // Phase A: thread t sums part[p][t] over all 256 p. Loads are coalesced
    // (consecutive t -> consecutive addresses) and ALL independent: full
    // unroll + 8 accumulators -> ~1-2 L2 latency rounds instead of 8.
    {
        float a0 = 0, a1 = 0, a2 = 0, a3 = 0, a4 = 0, a5 = 0, a6 = 0, a7 = 0;
#pragma unroll
        for (int p = 0; p < NBLK; p += 8) {
            a0 += part[(p + 0) * F_IN + t];
            a1 += part[(p + 1) * F_IN + t];
            a2 += part[(p + 2) * F_IN + t];
            a3 += part[(p + 3) * F_IN + t];
            a4 += part[(p + 4) * F_IN + t];
            a5 += part[(p + 5) * F_IN + t];
            a6 += part[(p + 6) * F_IN + t];
            a7 += part[(p + 7) * F_IN + t];
        }
        xbar[t] = (((a0 + a1) + (a2 + a3)) + ((a4 + a5) + (a6 + a7)))
                  * (1.0f / (float)N_ROWS);
    }
    __syncthreads();

    // Phase B: matvec. f = t&127, half = t>>7 owns 128 k's as 32 float4 loads
    // straight from L2/IC (no LDS staging detour), all independent.
    {
        const int f = t & (F_OUT - 1), kb = (t >> 7) * (F_IN / 2);
        const float4* wr = (const float4*)(W + (size_t)f * F_IN + kb);  // 32 float4
        const float4* xb = (const float4*)(xbar + kb);
        float c0 = 0, c1 = 0, c2 = 0, c3 = 0;
#pragma unroll
        for (int k = 0; k < 32; k += 4) {
            float4 w0 = wr[k + 0], x0 = xb[k + 0];
            float4 w1 = wr[k + 1], x1 = xb[k + 1];
            float4 w2 = wr[k + 2], x2 = xb[k + 2];
            float4 w3 = wr[k + 3], x3 = xb[k + 3];
            c0 += w0.x * x0.x + w0.y * x0.y + w0.z * x0.z + w0.w * x0.w;
            c1 += w1.x * x1.x + w1.y * x1.y + w1.z * x1.z + w1.w * x1.w;
            c2 += w2.x * x2.x + w2.y * x2.y + w2.z * x2.z + w2.w * x2.w;
            c3 += w3.x * x3.x + w3.y * x3.y + w3.z * x3.z + w3.w * x3.w;
        }
        psum[t] = (c0 + c1) + (c2 + c3);
    }
    __syncthreads();
    if (t < F_OUT)
        mrow[t] = (psum[t] + psum[t + 128]) + b[t];
    __syncthreads();

    // Phase C: this block's 32 output rows = 1024 float4, 4 coalesced stores/thread.
    const float4 v = ((const float4*)mrow)[t & (F_OUT / 4 - 1)];  // (t+j*256)&31 == t&31
    float4* o4 = (float4*)out + (size_t)blockIdx.x * (RPB * F_OUT / 4);
#pragma unroll
    for (int j = 0; j < 4; ++j)
        o4[t + j * 256] = v;
}

extern "C" void kernel_launch(void* const* d_in, const int* in_sizes, int n_in,
                              void* d_out, int out_size, void* d_ws, size_t ws_size,
                              hipStream_t stream) {
    const float* x = (const float*)d_in[0];   // [8192, 256]
    // d_in[1] = adj (unused)
    const float* W = (const float*)d_in[2];   // [128, 256]
    const float* b = (const float*)d_in[3];   // [128]
    // d_in[4] = Wa, d_in[5] = ba (algebraically dead)
    float* out  = (float*)d_out;              // [8192, 128]
    float* part = (float*)d_ws;               // NBLK*F_IN f32 = 256 KB

    gat_colsum<<<NBLK, 256, 0, stream>>>(x, part);
    gat_finish<<<NBLK, 256, 0, stream>>>(part, W, b, out);
}

// Round 9
// 15.872 us; speedup vs baseline: 1.2063x; 1.2063x over previous
//
#include <hip/hip_runtime.h>

// GraphAttentionLayer collapses algebraically:
//   a[i,j] = s[i] (constant over j) => softmax row = uniform 1/N
//   out[i] = mean_j h[j] = (mean_j x[j]) @ W.T + b   (identical for every row i)
//
// Shape: TWO plain kernel nodes. Measured ladder: 3 nodes=23.8, 2 nodes=20.35,
// tuned 2 nodes=16.62 (this shape), 256-block K2=19.15 (redundant-traffic
// regression: 96MB vs 32MB L2), all 1-node in-kernel-sync variants 54-70us
// (agent-scope fences force per-XCD L2 writeback -> kernel boundary is the
// cheapest global barrier). This round: round-7 revert + full-ILP phase-A.

#define N_ROWS 8192
#define F_IN   256
#define F_OUT  128
#define NB1    128
#define T1     512
#define RPB1   (N_ROWS / NB1)        // 64 rows per K1 block
#define NB2    128
#define T2     1024
#define RPB2   (N_ROWS / NB2)        // 64 out rows per K2 block

// K1: partial column sums. part[p][c] f32, p<128, c<256 (128 KB).
__global__ void __launch_bounds__(T1)
gat_colsum(const float* __restrict__ x, float* __restrict__ part) {
    __shared__ float cs2[2][F_IN];
    const int t = threadIdx.x, blk = blockIdx.x;
    const int col = t & (F_IN - 1), grp = t >> 8;          // grp in {0,1}
    const float* xp = x + ((size_t)blk * RPB1 + grp * 32) * F_IN + col;
    float s = 0.f;
#pragma unroll
    for (int r = 0; r < 32; ++r)
        s += xp[(size_t)r * F_IN];                         // coalesced (1KB/row)
    cs2[grp][col] = s;
    __syncthreads();
    if (t < F_IN)
        part[blk * F_IN + t] = cs2[0][t] + cs2[1][t];      // fixed order, f32
}

// K2: redundant deterministic reduce + matvec + broadcast (per-block identical).
__global__ void __launch_bounds__(T2, 1)
gat_finish(const float* __restrict__ part, const float* __restrict__ W,
           const float* __restrict__ b, float* __restrict__ out) {
    __shared__ float  Wl[F_OUT][F_IN + 1];   // 131.6 KB, +1 pad
    __shared__ double red[T2];               // reused: phase-A csp, phase-C psum
    __shared__ double cs_d[F_IN];
    __shared__ float  mrow[F_OUT];
    const int t = threadIdx.x;

    // Stage W -> LDS: 8192 float4 over 1024 threads = 8 coalesced iters.
    const float4* W4 = (const float4*)W;
#pragma unroll
    for (int j = 0; j < 8; ++j) {
        float4 v = W4[j * T2 + t];
        int idx = (j * T2 + t) * 4, f = idx >> 8, k = idx & 255;
        Wl[f][k] = v.x; Wl[f][k + 1] = v.y; Wl[f][k + 2] = v.z; Wl[f][k + 3] = v.w;
    }

    // Phase A: column-reduce part. f = t&255, quarter = t>>8 owns 32 p's.
    // Full unroll + 8 accumulators: all 32 loads independent -> ~1-2 L2
    // latency rounds (was 8 with unroll-2 x 4 acc). Coalesced across f.
    {
        const int f = t & (F_IN - 1), ps = (t >> 8) * 32;
        double a0 = 0, a1 = 0, a2 = 0, a3 = 0, a4 = 0, a5 = 0, a6 = 0, a7 = 0;
#pragma unroll
        for (int i = 0; i < 32; i += 8) {
            a0 += (double)part[(ps + i + 0) * F_IN + f];
            a1 += (double)part[(ps + i + 1) * F_IN + f];
            a2 += (double)part[(ps + i + 2) * F_IN + f];
            a3 += (double)part[(ps + i + 3) * F_IN + f];
            a4 += (double)part[(ps + i + 4) * F_IN + f];
            a5 += (double)part[(ps + i + 5) * F_IN + f];
            a6 += (double)part[(ps + i + 6) * F_IN + f];
            a7 += (double)part[(ps + i + 7) * F_IN + f];
        }
        red[t] = ((a0 + a1) + (a2 + a3)) + ((a4 + a5) + (a6 + a7));
    }
    __syncthreads();
    if (t < F_IN)
        cs_d[t] = ((red[t] + red[t + 256]) + (red[t + 512] + red[t + 768]))
                  * (1.0 / (double)N_ROWS);
    __syncthreads();   // also guards red[] reuse below

    // Phase C: matvec mrow[f] = dot(Wl[f], cs_d). f = t&127, oct = t>>7,
    // kb = oct*32 -> 32 MACs/thread from LDS. Wave has fixed oct, f spans 64
    // -> Wl banks 2-way (free); cs_d[k] is broadcast (free).
    {
        const int f = t & (F_OUT - 1), kb = (t >> 7) * 32;
        double c0 = 0, c1 = 0, c2 = 0, c3 = 0;
#pragma unroll 2
        for (int k = 0; k < 32; k += 4) {
            c0 += cs_d[kb + k + 0] * (double)Wl[f][kb + k + 0];
            c1 += cs_d[kb + k + 1] * (double)Wl[f][kb + k + 1];
            c2 += cs_d[kb + k + 2] * (double)Wl[f][kb + k + 2];
            c3 += cs_d[kb + k + 3] * (double)Wl[f][kb + k + 3];
        }
        red[t] = (c0 + c1) + (c2 + c3);
    }
    __syncthreads();
    if (t < F_OUT) {
        double m = ((red[t] + red[t + 128]) + (red[t + 256] + red[t + 384]))
                 + ((red[t + 512] + red[t + 640]) + (red[t + 768] + red[t + 896]));
        mrow[t] = (float)(m + (double)b[t]);
    }
    __syncthreads();

    // Broadcast: 64 rows x 128 f32 = 2048 float4; 1024 threads -> 2 stores each.
    const float4 v = ((const float4*)mrow)[t & (F_OUT / 4 - 1)];  // (t+j*1024)&31==t&31
    float4* o4 = (float4*)out + (size_t)blockIdx.x * (RPB2 * F_OUT / 4);
    o4[t] = v;
    o4[t + T2] = v;
}

extern "C" void kernel_launch(void* const* d_in, const int* in_sizes, int n_in,
                              void* d_out, int out_size, void* d_ws, size_t ws_size,
                              hipStream_t stream) {
    const float* x = (const float*)d_in[0];   // [8192, 256]
    // d_in[1] = adj (unused)
    const float* W = (const float*)d_in[2];   // [128, 256]
    const float* b = (const float*)d_in[3];   // [128]
    // d_in[4] = Wa, d_in[5] = ba (algebraically dead)
    float* out  = (float*)d_out;              // [8192, 128]
    float* part = (float*)d_ws;               // NB1*F_IN f32 = 128 KB

    gat_colsum<<<NB1, T1, 0, stream>>>(x, part);
    gat_finish<<<NB2, T2, 0, stream>>>(part, W, b, out);
}